// Round 1
// baseline (60.688 us; speedup 1.0000x reference)
//
#include <hip/hip_runtime.h>
#include <math.h>

// Problem constants
#define NN 128
#define LL 1024
#define HH 4
#define DD 64
#define NCHUNK 16
#define CROWS 64

// workspace layout (floats)
//   Z  : [64][256]                      @ 0          (16384)
//   Wt : [N][H][64(k)][8(j)]            @ 16384      (262144)
//   c  : [N][H][8]                      @ 278528     (4096)
//   Tp : [N][16][H*64]                  @ 282624     (524288)
#define WS_Z   0
#define WS_WT  16384
#define WS_C   278528
#define WS_TP  282624

// ---------------------------------------------------------------------------
// K12: blocks 0..63 compute Z[q,h,k] = sum_d Wu[q,h*64+d]*Wv[h*64+d,k]
//      blocks 64..191 compute per-n  v, w, c, Wt
// ---------------------------------------------------------------------------
__global__ void __launch_bounds__(256) precompute_kernel(
    const float* __restrict__ target, const float* __restrict__ memv,
    const float* __restrict__ Wk, const float* __restrict__ Wq,
    const float* __restrict__ Wv, const float* __restrict__ Wu,
    const float* __restrict__ W1, const float* __restrict__ b1,
    float* __restrict__ Z, float* __restrict__ Wt, float* __restrict__ cv)
{
    const int b = blockIdx.x;
    const int t = threadIdx.x;

    if (b < 64) {
        // Z part: q = b, t = h*64 + k
        const int q = b;
        const int h = t >> 6, k = t & 63;
        float s = 0.f;
        #pragma unroll 8
        for (int d = 0; d < 64; ++d)
            s = fmaf(Wu[q * 256 + h * 64 + d], Wv[(h * 64 + d) * 64 + k], s);
        Z[q * 256 + t] = s;
        return;
    }

    const int n = b - 64;
    __shared__ float t_lds[64];
    __shared__ float m_lds[64];
    __shared__ float v_lds[256];
    __shared__ float w_lds[4][8][64];

    if (t < 64) {
        t_lds[t] = target[n * 64 + t];
        m_lds[t] = memv[n * 64 + t];
    }
    __syncthreads();

    // v[h*64+d] = sum_k Wq[hd, k] * target[n, k]
    {
        float s = 0.f;
        #pragma unroll 8
        for (int k = 0; k < 64; ++k)
            s = fmaf(Wq[t * 64 + k], t_lds[k], s);
        v_lds[t] = s;
    }
    __syncthreads();

    // w[h][j][d] = -W1[j,d] - W1[j,128+d] + W1[j,64+d]*v[h,d] + W1[j,192+d]*m[d]
    {
        const int h = t >> 6, d = t & 63;
        const float vv = v_lds[t];
        const float mm = m_lds[d];
        #pragma unroll
        for (int j = 0; j < 8; ++j) {
            float wv = -W1[j * 256 + d] - W1[j * 256 + 128 + d];
            wv = fmaf(W1[j * 256 + 64 + d], vv, wv);
            wv = fmaf(W1[j * 256 + 192 + d], mm, wv);
            w_lds[h][j][d] = wv;
        }
    }
    // c[h][j] = b1[j] + sum_d (W1[j,d]*v[h,d] + W1[j,128+d]*m[d])
    if (t < 32) {
        const int h = t >> 3, j = t & 7;
        float s = b1[j];
        #pragma unroll 8
        for (int d = 0; d < 64; ++d) {
            s = fmaf(W1[j * 256 + d], v_lds[h * 64 + d], s);
            s = fmaf(W1[j * 256 + 128 + d], m_lds[d], s);
        }
        cv[(n * 4 + h) * 8 + j] = s;
    }
    __syncthreads();

    // Wt[n][h][k][j] = sum_d Wk[h*64+d, k] * w[h][j][d]
    for (int g = 0; g < 8; ++g) {
        const int o = g * 256 + t;          // o = h*512 + k*8 + j
        const int h = o >> 9;
        const int k = (o >> 3) & 63;
        const int j = o & 7;
        float s = 0.f;
        #pragma unroll 8
        for (int d = 0; d < 64; ++d)
            s = fmaf(Wk[(h * 64 + d) * 64 + k], w_lds[h][j][d], s);
        Wt[(size_t)n * 2048 + o] = s;
    }
}

// ---------------------------------------------------------------------------
// K3: per (n, 64-row chunk): scores -> sigmoid MLP -> att -> partial T
// wave = head h, lane = row l within chunk
// ---------------------------------------------------------------------------
__global__ void __launch_bounds__(256) main_kernel(
    const float* __restrict__ seq, const float* __restrict__ Wt,
    const float* __restrict__ cv, const float* __restrict__ W2,
    const float* __restrict__ b2, float* __restrict__ att_out,
    float* __restrict__ Tp)
{
    const int n = blockIdx.x >> 4;
    const int chunk = blockIdx.x & 15;
    const int l0 = chunk * CROWS;
    const int t = threadIdx.x;
    const int h = __builtin_amdgcn_readfirstlane(t >> 6);
    const int lane = t & 63;

    __shared__ float seq_t[64 * 65];  // [k][l], stride 65 -> conflict-free

    // stage + transpose 64 rows x 64 cols; global reads fully coalesced
    const float* srow = seq + ((size_t)n * LL + l0) * 64;
    #pragma unroll
    for (int g = 0; g < 4; ++g) {
        const int fidx = g * 256 + t;
        const int l = fidx >> 4;
        const int f = fidx & 15;
        const float4 vv = *reinterpret_cast<const float4*>(srow + l * 64 + f * 4);
        seq_t[(4 * f + 0) * 65 + l] = vv.x;
        seq_t[(4 * f + 1) * 65 + l] = vv.y;
        seq_t[(4 * f + 2) * 65 + l] = vv.z;
        seq_t[(4 * f + 3) * 65 + l] = vv.w;
    }
    __syncthreads();

    // scores: s[j] = c[n,h,j] + sum_k seq[l,k] * Wt[n,h,k,j]
    const float* wt = Wt + ((size_t)(n * 4 + h)) * 512;   // wave-uniform
    float acc[8];
    #pragma unroll
    for (int j = 0; j < 8; ++j) acc[j] = cv[(n * 4 + h) * 8 + j];

    for (int k = 0; k < 64; ++k) {
        const float sv = seq_t[k * 65 + lane];
        const float* w8 = wt + k * 8;                      // wave-uniform
        #pragma unroll
        for (int j = 0; j < 8; ++j) acc[j] = fmaf(sv, w8[j], acc[j]);
    }

    float sc = b2[0];
    #pragma unroll
    for (int j = 0; j < 8; ++j) {
        const float hm = 1.f / (1.f + __expf(-acc[j]));
        sc = fmaf(W2[j], hm, sc);
    }
    const float att = 1.f / (1.f + __expf(-sc));

    att_out[((size_t)n * LL + l0 + lane) * 4 + h] = att;

    // partial T[h][k]: lane = k; T_k = sum_l att[l] * seq[l, k]
    float tacc = 0.f;
    #pragma unroll 8
    for (int l = 0; l < 64; ++l) {
        const float a = __shfl(att, l);
        tacc = fmaf(a, seq_t[lane * 65 + l], tacc);
    }
    Tp[(((size_t)n * NCHUNK + chunk) * 4 + h) * 64 + lane] = tacc;
}

// ---------------------------------------------------------------------------
// K4: reduce partial T over chunks, then output[n,q] = bu[q] + sum_hk T*Z
// ---------------------------------------------------------------------------
__global__ void __launch_bounds__(256) finalize_kernel(
    const float* __restrict__ Tp, const float* __restrict__ Z,
    const float* __restrict__ bu, float* __restrict__ out)
{
    const int n = blockIdx.x;
    const int t = threadIdx.x;
    __shared__ float T_lds[256];

    float s = 0.f;
    #pragma unroll
    for (int c = 0; c < NCHUNK; ++c)
        s += Tp[((size_t)n * NCHUNK + c) * 256 + t];
    T_lds[t] = s;
    __syncthreads();

    if (t < 64) {
        float o = bu[t];
        #pragma unroll 8
        for (int p = 0; p < 256; ++p)
            o = fmaf(T_lds[p], Z[t * 256 + p], o);
        out[n * 64 + t] = o;
    }
}

extern "C" void kernel_launch(void* const* d_in, const int* in_sizes, int n_in,
                              void* d_out, int out_size, void* d_ws, size_t ws_size,
                              hipStream_t stream) {
    const float* seq    = (const float*)d_in[0];
    const float* target = (const float*)d_in[1];
    const float* memv   = (const float*)d_in[2];
    const float* Wk     = (const float*)d_in[3];
    const float* Wq     = (const float*)d_in[4];
    const float* Wv     = (const float*)d_in[5];
    const float* Wu     = (const float*)d_in[6];
    const float* bu     = (const float*)d_in[7];
    const float* W1     = (const float*)d_in[8];
    const float* b1     = (const float*)d_in[9];
    const float* W2     = (const float*)d_in[10];
    const float* b2     = (const float*)d_in[11];

    float* out = (float*)d_out;             // [128*64]
    float* att = out + NN * DD;             // [128*1024*4]

    float* ws = (float*)d_ws;
    float* Z  = ws + WS_Z;
    float* Wt = ws + WS_WT;
    float* cv = ws + WS_C;
    float* Tp = ws + WS_TP;

    precompute_kernel<<<192, 256, 0, stream>>>(target, memv, Wk, Wq, Wv, Wu, W1, b1,
                                               Z, Wt, cv);
    main_kernel<<<NN * NCHUNK, 256, 0, stream>>>(seq, Wt, cv, W2, b2, att, Tp);
    finalize_kernel<<<NN, 256, 0, stream>>>(Tp, Z, bu, out);
}

// Round 2
// 52.392 us; speedup vs baseline: 1.1583x; 1.1583x over previous
//
#include <hip/hip_runtime.h>
#include <math.h>

// Problem constants
#define NN 128
#define LL 1024
#define HH 4
#define DD 64
#define NCHUNK 16
#define CROWS 64

// workspace layout (floats)
//   Zt : [256(p=h*64+k)][64(q)]         @ 0          (16384)
//   Wt : [N][H][64(k)][8(j)]            @ 16384      (262144)
//   c  : [N][H][8]                      @ 278528     (4096)
#define WS_ZT  0
#define WS_WT  16384
#define WS_C   278528

// ---------------------------------------------------------------------------
// K1: blocks 0..63   : Zt[p,q] = sum_d Wu[q, h*64+d] * Wv[h*64+d, k]  (p=h*64+k)
//     blocks 64..191 : per-n  v, w, c, Wt   +  out[n,:] = bu
// ---------------------------------------------------------------------------
__global__ void __launch_bounds__(256) precompute_kernel(
    const float* __restrict__ target, const float* __restrict__ memv,
    const float* __restrict__ Wk, const float* __restrict__ Wq,
    const float* __restrict__ Wv, const float* __restrict__ Wu,
    const float* __restrict__ W1, const float* __restrict__ b1,
    const float* __restrict__ bu,
    float* __restrict__ Zt, float* __restrict__ Wt, float* __restrict__ cv,
    float* __restrict__ out)
{
    const int b = blockIdx.x;
    const int t = threadIdx.x;

    if (b < 64) {
        // q = b; t = p = h*64 + k
        const int q = b;
        const int h = t >> 6, k = t & 63;
        float s = 0.f;
        #pragma unroll 8
        for (int d = 0; d < 64; ++d)
            s = fmaf(Wu[q * 256 + h * 64 + d], Wv[(h * 64 + d) * 64 + k], s);
        Zt[t * 64 + q] = s;   // transposed store (one-time, coalescing irrelevant)
        return;
    }

    const int n = b - 64;
    __shared__ float t_lds[64];
    __shared__ float m_lds[64];
    __shared__ float v_lds[256];
    __shared__ float w_lds[4][8][65];   // pad 64->65: Wt loop reads bank (j+d)%32

    if (t < 64) {
        t_lds[t] = target[n * 64 + t];
        m_lds[t] = memv[n * 64 + t];
        out[n * 64 + t] = bu[t];        // init for K2's atomic accumulation
    }
    __syncthreads();

    // v[h*64+d] = sum_k Wq[hd, k] * target[n, k]
    {
        float s = 0.f;
        #pragma unroll 8
        for (int k = 0; k < 64; ++k)
            s = fmaf(Wq[t * 64 + k], t_lds[k], s);
        v_lds[t] = s;
    }
    __syncthreads();

    // w[h][j][d] = -W1[j,d] - W1[j,128+d] + W1[j,64+d]*v[h,d] + W1[j,192+d]*m[d]
    {
        const int h = t >> 6, d = t & 63;
        const float vv = v_lds[t];
        const float mm = m_lds[d];
        #pragma unroll
        for (int j = 0; j < 8; ++j) {
            float wv = -W1[j * 256 + d] - W1[j * 256 + 128 + d];
            wv = fmaf(W1[j * 256 + 64 + d], vv, wv);
            wv = fmaf(W1[j * 256 + 192 + d], mm, wv);
            w_lds[h][j][d] = wv;
        }
    }
    // c[h][j] = b1[j] + sum_d (W1[j,d]*v[h,d] + W1[j,128+d]*m[d])
    if (t < 32) {
        const int h = t >> 3, j = t & 7;
        float s = b1[j];
        #pragma unroll 8
        for (int d = 0; d < 64; ++d) {
            s = fmaf(W1[j * 256 + d], v_lds[h * 64 + d], s);
            s = fmaf(W1[j * 256 + 128 + d], m_lds[d], s);
        }
        cv[(n * 4 + h) * 8 + j] = s;
    }
    __syncthreads();

    // Wt[n][h][k][j] = sum_d Wk[h*64+d, k] * w[h][j][d]
    for (int g = 0; g < 8; ++g) {
        const int o = g * 256 + t;          // o = h*512 + k*8 + j
        const int h = o >> 9;
        const int k = (o >> 3) & 63;
        const int j = o & 7;
        float s = 0.f;
        #pragma unroll 8
        for (int d = 0; d < 64; ++d)
            s = fmaf(Wk[(h * 64 + d) * 64 + k], w_lds[h][j][d], s);
        Wt[(size_t)n * 2048 + o] = s;
    }
}

// ---------------------------------------------------------------------------
// K2: per (n, 64-row chunk): scores -> sigmoid MLP -> att -> T_chunk ->
//     out-contribution GEMV -> atomicAdd into out.
// wave = head h, lane = row l (score phase) / k (T phase)
// ---------------------------------------------------------------------------
__global__ void __launch_bounds__(256) main_kernel(
    const float* __restrict__ seq, const float* __restrict__ Wt,
    const float* __restrict__ cv, const float* __restrict__ W2,
    const float* __restrict__ b2, const float* __restrict__ Zt,
    float* __restrict__ att_out, float* __restrict__ out)
{
    const int n = blockIdx.x >> 4;
    const int chunk = blockIdx.x & 15;
    const int l0 = chunk * CROWS;
    const int t = threadIdx.x;
    const int h = __builtin_amdgcn_readfirstlane(t >> 6);
    const int lane = t & 63;

    __shared__ float seq_t[64 * 65];   // [k][l], banks (k+l)%32 -> conflict-free
    __shared__ float att_lds[256];     // [h][l]
    __shared__ float T_lds[256];       // [h][k]
    __shared__ float o_lds[256];       // [wave][q]

    // stage + transpose 64 rows x 64 cols; global reads fully coalesced
    const float* srow = seq + ((size_t)n * LL + l0) * 64;
    #pragma unroll
    for (int g = 0; g < 4; ++g) {
        const int fidx = g * 256 + t;
        const int l = fidx >> 4;
        const int f = fidx & 15;
        const float4 vv = *reinterpret_cast<const float4*>(srow + l * 64 + f * 4);
        seq_t[(4 * f + 0) * 65 + l] = vv.x;
        seq_t[(4 * f + 1) * 65 + l] = vv.y;
        seq_t[(4 * f + 2) * 65 + l] = vv.z;
        seq_t[(4 * f + 3) * 65 + l] = vv.w;
    }
    __syncthreads();

    // scores: s[j] = c[n,h,j] + sum_k seq[l,k] * Wt[n,h,k,j]   (wt wave-uniform)
    const float* wt = Wt + ((size_t)(n * 4 + h)) * 512;
    float acc[8];
    #pragma unroll
    for (int j = 0; j < 8; ++j) acc[j] = cv[(n * 4 + h) * 8 + j];

    for (int k = 0; k < 64; ++k) {
        const float sv = seq_t[k * 65 + lane];
        const float* w8 = wt + k * 8;
        #pragma unroll
        for (int j = 0; j < 8; ++j) acc[j] = fmaf(sv, w8[j], acc[j]);
    }

    float sc = b2[0];
    #pragma unroll
    for (int j = 0; j < 8; ++j) {
        const float hm = 1.f / (1.f + __expf(-acc[j]));
        sc = fmaf(W2[j], hm, sc);
    }
    const float att = 1.f / (1.f + __expf(-sc));

    att_lds[h * 64 + lane] = att;      // banks lane%32 -> 2-way (free)
    __syncthreads();

    // coalesced att store: block covers 256 contiguous floats of att_out
    att_out[((size_t)n * LL + l0) * 4 + t] = att_lds[(t & 3) * 64 + (t >> 2)];

    // T[h][k]: lane = k; T_k = sum_l att[h][l] * seq[l, k]
    float tacc = 0.f;
    #pragma unroll 8
    for (int l = 0; l < 64; ++l) {
        const float a = att_lds[h * 64 + l];        // wave-uniform broadcast
        tacc = fmaf(a, seq_t[lane * 65 + l], tacc);
    }
    T_lds[h * 64 + lane] = tacc;
    __syncthreads();

    // out contribution: oc[q] = sum_p T[p] * Zt[p][q]; wave w sums p-slice
    {
        const int q = t & 63;
        const int w = t >> 6;
        float s = 0.f;
        #pragma unroll 8
        for (int i = 0; i < 64; ++i) {
            const int p = w * 64 + i;
            s = fmaf(T_lds[p], Zt[p * 64 + q], s);  // Zt load lane-coalesced
        }
        o_lds[t] = s;
    }
    __syncthreads();

    if (t < 64) {
        const float s = o_lds[t] + o_lds[64 + t] + o_lds[128 + t] + o_lds[192 + t];
        atomicAdd(out + n * 64 + t, s);
    }
}

extern "C" void kernel_launch(void* const* d_in, const int* in_sizes, int n_in,
                              void* d_out, int out_size, void* d_ws, size_t ws_size,
                              hipStream_t stream) {
    const float* seq    = (const float*)d_in[0];
    const float* target = (const float*)d_in[1];
    const float* memv   = (const float*)d_in[2];
    const float* Wk     = (const float*)d_in[3];
    const float* Wq     = (const float*)d_in[4];
    const float* Wv     = (const float*)d_in[5];
    const float* Wu     = (const float*)d_in[6];
    const float* bu     = (const float*)d_in[7];
    const float* W1     = (const float*)d_in[8];
    const float* b1     = (const float*)d_in[9];
    const float* W2     = (const float*)d_in[10];
    const float* b2     = (const float*)d_in[11];

    float* out = (float*)d_out;             // [128*64]
    float* att = out + NN * DD;             // [128*1024*4]

    float* ws = (float*)d_ws;
    float* Zt = ws + WS_ZT;
    float* Wt = ws + WS_WT;
    float* cv = ws + WS_C;

    precompute_kernel<<<192, 256, 0, stream>>>(target, memv, Wk, Wq, Wv, Wu, W1, b1,
                                               bu, Zt, Wt, cv, out);
    main_kernel<<<NN * NCHUNK, 256, 0, stream>>>(seq, Wt, cv, W2, b2, Zt, att, out);
}

// Round 3
// 42.733 us; speedup vs baseline: 1.4201x; 1.2260x over previous
//
#include <hip/hip_runtime.h>
#include <math.h>

// Problem constants
#define NN 128
#define LL 1024
#define HH 4
#define DD 64
#define NCHUNK 8          // chunks per n (128 rows each)
#define CROWS 128

// workspace layout (floats)
//   Wt : [N][H][64(k)][8(j)]   @ 0       (262144)
//   cv : [N][H][8]             @ 262144  (4096)
#define WS_WT  0
#define WS_C   262144

__device__ __forceinline__ float sigm(float x) {
    return __builtin_amdgcn_rcpf(1.f + __expf(-x));
}

// ---------------------------------------------------------------------------
// K1: blocks 0..31   : out[n,q] = bu[q]  (init for K2's atomics)
//     blocks 32..543 : per-(n,h)  v, w, c, Wt   -- 4x more parallel than R2
// ---------------------------------------------------------------------------
__global__ void __launch_bounds__(256) precompute_kernel(
    const float* __restrict__ target, const float* __restrict__ memv,
    const float* __restrict__ Wk, const float* __restrict__ Wq,
    const float* __restrict__ W1, const float* __restrict__ b1,
    const float* __restrict__ bu,
    float* __restrict__ Wtg, float* __restrict__ cvg, float* __restrict__ out)
{
    const int b = blockIdx.x;
    const int t = threadIdx.x;

    if (b < 32) {
        const int idx = b * 256 + t;          // 8192 = 128*64
        out[idx] = bu[idx & 63];
        return;
    }

    const int nh = b - 32;
    const int n = nh >> 2, h = nh & 3;

    __shared__ float tl[64], ml[64], vh[64], cp[64];
    __shared__ float vp[256];
    __shared__ float wh[8][68];               // pad 68: conflict-free j-spread

    if (t < 64)  tl[t] = target[n * 64 + t];
    else if (t < 128) ml[t - 64] = memv[n * 64 + (t - 64)];
    __syncthreads();

    // v[d] = sum_k Wq[h*64+d, k] * target[k]   (4 partial k-slices)
    {
        const int d = t & 63, kq = t >> 6;
        const float4* wq4 = reinterpret_cast<const float4*>(Wq + (h * 64 + d) * 64 + kq * 16);
        const float4* tl4 = reinterpret_cast<const float4*>(tl + kq * 16);
        float s = 0.f;
        #pragma unroll
        for (int c = 0; c < 4; ++c) {
            const float4 a = wq4[c], bb = tl4[c];
            s = fmaf(a.x, bb.x, s); s = fmaf(a.y, bb.y, s);
            s = fmaf(a.z, bb.z, s); s = fmaf(a.w, bb.w, s);
        }
        vp[t] = s;
    }
    __syncthreads();
    if (t < 64) vh[t] = vp[t] + vp[64 + t] + vp[128 + t] + vp[192 + t];
    __syncthreads();

    // w[j][d] = -W1[j,d] - W1[j,128+d] + W1[j,64+d]*v[d] + W1[j,192+d]*m[d]
    {
        const int d = t & 63, jh = t >> 6;
        const float vv = vh[d], mm = ml[d];
        #pragma unroll
        for (int r = 0; r < 2; ++r) {
            const int j = jh + r * 4;
            float wv = -W1[j * 256 + d] - W1[j * 256 + 128 + d];
            wv = fmaf(W1[j * 256 + 64 + d], vv, wv);
            wv = fmaf(W1[j * 256 + 192 + d], mm, wv);
            wh[j][d] = wv;
        }
    }
    // c[j] partials
    {
        const int j = t >> 3, sl = t & 7;
        float s = 0.f;
        #pragma unroll
        for (int d8 = 0; d8 < 8; ++d8) {
            const int d = sl * 8 + d8;
            s = fmaf(W1[j * 256 + d], vh[d], s);
            s = fmaf(W1[j * 256 + 128 + d], ml[d], s);
        }
        cp[t] = s;
    }
    __syncthreads();
    if (t < 8) {
        float s = b1[t];
        #pragma unroll
        for (int sl = 0; sl < 8; ++sl) s += cp[t * 8 + sl];
        cvg[(n * 4 + h) * 8 + t] = s;
    }

    // Wt[k][j] = sum_d Wk[h*64+d, k] * w[j][d]
    #pragma unroll
    for (int rep = 0; rep < 2; ++rep) {
        const int o = rep * 256 + t;
        const int k = o >> 3, j = o & 7;
        float s = 0.f;
        #pragma unroll 8
        for (int d = 0; d < 64; ++d)
            s = fmaf(Wk[(h * 64 + d) * 64 + k], wh[j][d], s);
        Wtg[((size_t)(n * 4 + h) * 64 + k) * 8 + j] = s;
    }
}

// ---------------------------------------------------------------------------
// K2: per (n, 128-row chunk): scores (2 heads/thread, wt via uniform s_loads)
//     -> sigmoid MLP -> att -> T -> U = T*Wv^T -> out += U*Wu^T (atomic)
// ---------------------------------------------------------------------------
__global__ void __launch_bounds__(256, 4) main_kernel(
    const float* __restrict__ seq, const float* __restrict__ Wtg,
    const float* __restrict__ cvg, const float* __restrict__ W2,
    const float* __restrict__ b2, const float* __restrict__ Wv,
    const float* __restrict__ Wu,
    float* __restrict__ att_out, float* __restrict__ out)
{
    const int n = blockIdx.x >> 3;
    const int chunk = blockIdx.x & 7;
    const int l0 = chunk * CROWS;
    const int t = threadIdx.x;
    const int lane = t & 63;

    __shared__ float seq_t[64 * 129];   // [feat k][row l], pad 129: banks (k+l)%32
    __shared__ float att_l[4 * 128];    // [h][l]
    __shared__ float T_l[256];          // [h][k]
    __shared__ float U_l[256];          // [hd]
    __shared__ float op[256];           // [quarter][q]

    // ---- stage seq chunk as [k][l], global reads coalesced ----
    const float* srow = seq + ((size_t)n * LL + l0) * 64;
    #pragma unroll
    for (int g = 0; g < 8; ++g) {
        const int fidx = g * 256 + t;
        const int l = fidx >> 4;
        const int f = fidx & 15;
        const float4 vv = *reinterpret_cast<const float4*>(srow + l * 64 + f * 4);
        seq_t[(4 * f + 0) * 129 + l] = vv.x;
        seq_t[(4 * f + 1) * 129 + l] = vv.y;
        seq_t[(4 * f + 2) * 129 + l] = vv.z;
        seq_t[(4 * f + 3) * 129 + l] = vv.w;
    }
    __syncthreads();

    // ---- scores: thread = (row l, head-pair {hp, hp+2}) ----
    const int w = t >> 6;
    const int hp = __builtin_amdgcn_readfirstlane(w & 1);
    const int lhalf = __builtin_amdgcn_readfirstlane(w >> 1);
    const int l = lhalf * 64 + lane;

    const float4* wtA = reinterpret_cast<const float4*>(Wtg + (size_t)(n * 4 + hp) * 512);
    const float4* wtB = reinterpret_cast<const float4*>(Wtg + (size_t)(n * 4 + hp + 2) * 512);
    const float4* cvA = reinterpret_cast<const float4*>(cvg + (n * 4 + hp) * 8);
    const float4* cvB = reinterpret_cast<const float4*>(cvg + (n * 4 + hp + 2) * 8);

    float accA[8], accB[8];
    {
        const float4 c0 = cvA[0], c1 = cvA[1], c2 = cvB[0], c3 = cvB[1];
        accA[0]=c0.x; accA[1]=c0.y; accA[2]=c0.z; accA[3]=c0.w;
        accA[4]=c1.x; accA[5]=c1.y; accA[6]=c1.z; accA[7]=c1.w;
        accB[0]=c2.x; accB[1]=c2.y; accB[2]=c2.z; accB[3]=c2.w;
        accB[4]=c3.x; accB[5]=c3.y; accB[6]=c3.z; accB[7]=c3.w;
    }

    #pragma unroll 4
    for (int k = 0; k < 64; ++k) {
        const float sv = seq_t[k * 129 + l];
        const float4 a0 = wtA[k * 2], a1 = wtA[k * 2 + 1];   // uniform -> s_load
        const float4 b0 = wtB[k * 2], b1v = wtB[k * 2 + 1];
        accA[0]=fmaf(sv,a0.x,accA[0]); accA[1]=fmaf(sv,a0.y,accA[1]);
        accA[2]=fmaf(sv,a0.z,accA[2]); accA[3]=fmaf(sv,a0.w,accA[3]);
        accA[4]=fmaf(sv,a1.x,accA[4]); accA[5]=fmaf(sv,a1.y,accA[5]);
        accA[6]=fmaf(sv,a1.z,accA[6]); accA[7]=fmaf(sv,a1.w,accA[7]);
        accB[0]=fmaf(sv,b0.x,accB[0]); accB[1]=fmaf(sv,b0.y,accB[1]);
        accB[2]=fmaf(sv,b0.z,accB[2]); accB[3]=fmaf(sv,b0.w,accB[3]);
        accB[4]=fmaf(sv,b1v.x,accB[4]); accB[5]=fmaf(sv,b1v.y,accB[5]);
        accB[6]=fmaf(sv,b1v.z,accB[6]); accB[7]=fmaf(sv,b1v.w,accB[7]);
    }

    {
        const float4 w20 = *reinterpret_cast<const float4*>(W2);
        const float4 w21 = *reinterpret_cast<const float4*>(W2 + 4);
        const float bb = b2[0];
        float scA = bb, scB = bb;
        scA = fmaf(w20.x, sigm(accA[0]), scA); scA = fmaf(w20.y, sigm(accA[1]), scA);
        scA = fmaf(w20.z, sigm(accA[2]), scA); scA = fmaf(w20.w, sigm(accA[3]), scA);
        scA = fmaf(w21.x, sigm(accA[4]), scA); scA = fmaf(w21.y, sigm(accA[5]), scA);
        scA = fmaf(w21.z, sigm(accA[6]), scA); scA = fmaf(w21.w, sigm(accA[7]), scA);
        scB = fmaf(w20.x, sigm(accB[0]), scB); scB = fmaf(w20.y, sigm(accB[1]), scB);
        scB = fmaf(w20.z, sigm(accB[2]), scB); scB = fmaf(w20.w, sigm(accB[3]), scB);
        scB = fmaf(w21.x, sigm(accB[4]), scB); scB = fmaf(w21.y, sigm(accB[5]), scB);
        scB = fmaf(w21.z, sigm(accB[6]), scB); scB = fmaf(w21.w, sigm(accB[7]), scB);
        att_l[hp * 128 + l]       = sigm(scA);
        att_l[(hp + 2) * 128 + l] = sigm(scB);
    }
    __syncthreads();

    // ---- coalesced att store: 512 contiguous floats ----
    {
        float* dst = att_out + ((size_t)n * LL + l0) * 4;
        #pragma unroll
        for (int r = 0; r < 2; ++r) {
            const int idx = r * 256 + t;
            dst[idx] = att_l[(idx & 3) * 128 + (idx >> 2)];
        }
    }

    // ---- T[h][k] = sum_l att[h][l] * seq[l][k] ----
    {
        const int h = t >> 6, k = lane;
        float tacc = 0.f;
        #pragma unroll 4
        for (int li = 0; li < 128; ++li) {
            const float a = att_l[h * 128 + li];        // same-address broadcast
            tacc = fmaf(a, seq_t[k * 129 + li], tacc);  // banks (k+li)%32: free
        }
        T_l[t] = tacc;
    }
    __syncthreads();

    // ---- U[hd] = sum_k T[h][k] * Wv[hd][k] ----
    {
        const int h = t >> 6;
        const float4* wv4 = reinterpret_cast<const float4*>(Wv + t * 64);
        const float4* t4  = reinterpret_cast<const float4*>(T_l + h * 64);
        float s = 0.f;
        #pragma unroll
        for (int kq = 0; kq < 16; ++kq) {
            const float4 a = wv4[kq], bb = t4[kq];      // t4 uniform per wave
            s = fmaf(a.x, bb.x, s); s = fmaf(a.y, bb.y, s);
            s = fmaf(a.z, bb.z, s); s = fmaf(a.w, bb.w, s);
        }
        U_l[t] = s;
    }
    __syncthreads();

    // ---- out[q] += sum_hd U[hd] * Wu[q][hd]  (4-way split + atomic) ----
    {
        const int q = t & 63, qr = t >> 6;
        const float4* wu4 = reinterpret_cast<const float4*>(Wu + q * 256 + qr * 64);
        const float4* u4  = reinterpret_cast<const float4*>(U_l + qr * 64);
        float s = 0.f;
        #pragma unroll
        for (int i = 0; i < 16; ++i) {
            const float4 a = wu4[i], bb = u4[i];        // u4 uniform per wave
            s = fmaf(a.x, bb.x, s); s = fmaf(a.y, bb.y, s);
            s = fmaf(a.z, bb.z, s); s = fmaf(a.w, bb.w, s);
        }
        op[t] = s;
    }
    __syncthreads();
    if (t < 64) {
        const float s = op[t] + op[64 + t] + op[128 + t] + op[192 + t];
        atomicAdd(out + n * 64 + t, s);
    }
}

extern "C" void kernel_launch(void* const* d_in, const int* in_sizes, int n_in,
                              void* d_out, int out_size, void* d_ws, size_t ws_size,
                              hipStream_t stream) {
    const float* seq    = (const float*)d_in[0];
    const float* target = (const float*)d_in[1];
    const float* memv   = (const float*)d_in[2];
    const float* Wk     = (const float*)d_in[3];
    const float* Wq     = (const float*)d_in[4];
    const float* Wv     = (const float*)d_in[5];
    const float* Wu     = (const float*)d_in[6];
    const float* bu     = (const float*)d_in[7];
    const float* W1     = (const float*)d_in[8];
    const float* b1     = (const float*)d_in[9];
    const float* W2     = (const float*)d_in[10];
    const float* b2     = (const float*)d_in[11];

    float* out = (float*)d_out;             // [128*64]
    float* att = out + NN * DD;             // [128*1024*4]

    float* ws  = (float*)d_ws;
    float* Wtg = ws + WS_WT;
    float* cvg = ws + WS_C;

    precompute_kernel<<<544, 256, 0, stream>>>(target, memv, Wk, Wq, W1, b1, bu,
                                               Wtg, cvg, out);
    main_kernel<<<NN * NCHUNK, 256, 0, stream>>>(seq, Wtg, cvg, W2, b2, Wv, Wu,
                                                 att, out);
}

// Round 4
// 32.776 us; speedup vs baseline: 1.8516x; 1.3038x over previous
//
#include <hip/hip_runtime.h>
#include <math.h>

// Problem constants
#define NN 128
#define LL 1024
#define HH 4
#define DD 64
#define NCHUNK 8          // chunks per n (128 rows each)
#define CROWS 128

// workspace layout (floats)
//   Wt : [N][H][64(k)][8(j)]   @ 0       (262144)
//   cv : [N][H][8]             @ 262144  (4096)
//   Zt : [256(p=h*64+k)][64q]  @ 266240  (16384)
#define WS_WT  0
#define WS_C   262144
#define WS_ZT  266240

__device__ __forceinline__ float sigm(float x) {
    return __builtin_amdgcn_rcpf(1.f + __expf(-x));
}

// ---------------------------------------------------------------------------
// K1: blocks 0..31   : out[n,q] = bu[q]          (init for K2's atomics)
//     blocks 32..95  : Zt[p,q]  = sum_d Wu[q,h*64+d]*Wv[h*64+d,k]  (p=h*64+k)
//     blocks 96..607 : per-(n,h) v, w, c, Wt     (all phases lane-coalesced)
// ---------------------------------------------------------------------------
__global__ void __launch_bounds__(256) precompute_kernel(
    const float* __restrict__ target, const float* __restrict__ memv,
    const float* __restrict__ Wk, const float* __restrict__ Wq,
    const float* __restrict__ Wv, const float* __restrict__ Wu,
    const float* __restrict__ W1, const float* __restrict__ b1,
    const float* __restrict__ bu,
    float* __restrict__ Wtg, float* __restrict__ cvg, float* __restrict__ Zt,
    float* __restrict__ out)
{
    const int b = blockIdx.x;
    const int t = threadIdx.x;

    if (b < 32) {
        const int idx = b * 256 + t;          // 8192 = 128*64
        out[idx] = bu[idx & 63];
        return;
    }
    if (b < 96) {
        // Zt: q = b-32; t = p = h*64+k. Wv read coalesced (k on lanes).
        const int q = b - 32;
        const int h = t >> 6, k = t & 63;
        float s = 0.f;
        #pragma unroll 8
        for (int d = 0; d < 64; ++d)
            s = fmaf(Wu[q * 256 + h * 64 + d], Wv[(h * 64 + d) * 64 + k], s);
        Zt[t * 64 + q] = s;                   // one-time scatter, fine
        return;
    }

    const int nh = b - 96;
    const int n = nh >> 2, h = nh & 3;

    __shared__ __align__(16) float tl[64];
    __shared__ __align__(16) float ml[64];
    __shared__ float vh[64];
    __shared__ float wh[64 * 8];              // [d][j]
    __shared__ float cp[64];

    if (t < 64)       tl[t] = target[n * 64 + t];
    else if (t < 128) ml[t - 64] = memv[n * 64 + (t - 64)];
    __syncthreads();

    // ---- v[d] = sum_k Wq[h*64+d, k] * target[k]; (d, k-quarter) on threads ----
    {
        const int d = t >> 2, kq = t & 3;
        const float4* wq4 = reinterpret_cast<const float4*>(Wq + (h * 64 + d) * 64 + kq * 16);
        const float4* tl4 = reinterpret_cast<const float4*>(tl + kq * 16);
        float s = 0.f;
        #pragma unroll
        for (int c = 0; c < 4; ++c) {
            const float4 a = wq4[c], bb = tl4[c];
            s = fmaf(a.x, bb.x, s); s = fmaf(a.y, bb.y, s);
            s = fmaf(a.z, bb.z, s); s = fmaf(a.w, bb.w, s);
        }
        s += __shfl_xor(s, 1);
        s += __shfl_xor(s, 2);
        if (kq == 0) vh[d] = s;
    }
    __syncthreads();

    // ---- w[d][j] = -W1[j,d] - W1[j,128+d] + W1[j,64+d]*v[d] + W1[j,192+d]*m[d] ----
    {
        const int d = t & 63, jh = t >> 6;
        const float vv = vh[d], mm = ml[d];
        #pragma unroll
        for (int r = 0; r < 2; ++r) {
            const int j = jh + r * 4;
            float wv = -W1[j * 256 + d] - W1[j * 256 + 128 + d];
            wv = fmaf(W1[j * 256 + 64 + d], vv, wv);
            wv = fmaf(W1[j * 256 + 192 + d], mm, wv);
            wh[d * 8 + j] = wv;
        }
    }
    // ---- c[j] partials ----
    if (t < 64) {
        const int j = t >> 3, sl = t & 7;
        float s = 0.f;
        #pragma unroll
        for (int d8 = 0; d8 < 8; ++d8) {
            const int d = sl * 8 + d8;
            s = fmaf(W1[j * 256 + d], vh[d], s);
            s = fmaf(W1[j * 256 + 128 + d], ml[d], s);
        }
        cp[t] = s;
    }
    __syncthreads();
    if (t < 8) {
        float s = b1[t];
        #pragma unroll
        for (int sl = 0; sl < 8; ++sl) s += cp[t * 8 + sl];
        cvg[(n * 4 + h) * 8 + t] = s;
    }

    // ---- Wt[k][j] = sum_d Wk[h*64+d, k] * w[d][j]; k on lanes (coalesced) ----
    {
        const int k = t & 63, jp = t >> 6;
        float s0 = 0.f, s1 = 0.f;
        #pragma unroll 8
        for (int d = 0; d < 64; ++d) {
            const float wk = Wk[(h * 64 + d) * 64 + k];
            s0 = fmaf(wk, wh[d * 8 + jp], s0);       // uniform LDS reads
            s1 = fmaf(wk, wh[d * 8 + jp + 4], s1);
        }
        float* dst = Wtg + ((size_t)(n * 4 + h) * 64 + k) * 8;
        dst[jp] = s0;
        dst[jp + 4] = s1;
    }
}

// ---------------------------------------------------------------------------
// K2: per (n, 128-row chunk): Wt/cv -> LDS; scores (2 heads/thread, uniform
//     LDS b128 weight reads) -> sigmoid MLP -> att -> T -> out += T*Zt (atomic)
// ---------------------------------------------------------------------------
__global__ void __launch_bounds__(256, 3) main_kernel(
    const float* __restrict__ seq, const float* __restrict__ Wtg,
    const float* __restrict__ cvg, const float* __restrict__ W2,
    const float* __restrict__ b2, const float* __restrict__ Zt,
    float* __restrict__ att_out, float* __restrict__ out)
{
    const int n = blockIdx.x >> 3;
    const int chunk = blockIdx.x & 7;
    const int l0 = chunk * CROWS;
    const int t = threadIdx.x;
    const int lane = t & 63;
    const int w = t >> 6;

    __shared__ float seq_t[64 * 129];              // [k][l] stride 129: 33 KB
    __shared__ __align__(16) float wt[4 * 64 * 8]; // [h][k][j]: 8 KB
    __shared__ float cvl[32];
    __shared__ __align__(16) float att_l[4 * 128]; // [h][l]
    __shared__ float T_l[256];                     // [h*64+k] = [p]
    __shared__ float op[256];
    // total ~45.4 KB -> 3 blocks/CU

    // ---- issue Wt/cv loads first, then seq loads; write LDS after ----
    const float4* wtg4 = reinterpret_cast<const float4*>(Wtg + (size_t)n * 2048);
    const float4 wtv0 = wtg4[t];
    const float4 wtv1 = wtg4[256 + t];
    float cvv = 0.f;
    if (t < 32) cvv = cvg[n * 32 + t];

    const float* srow = seq + ((size_t)n * LL + l0) * 64;
    float4 sv[8];
    #pragma unroll
    for (int g = 0; g < 8; ++g) {
        const int fidx = g * 256 + t;
        const int l = fidx >> 4;
        const int f = fidx & 15;
        sv[g] = *reinterpret_cast<const float4*>(srow + l * 64 + f * 4);
    }

    reinterpret_cast<float4*>(wt)[t] = wtv0;
    reinterpret_cast<float4*>(wt)[256 + t] = wtv1;
    if (t < 32) cvl[t] = cvv;
    #pragma unroll
    for (int g = 0; g < 8; ++g) {
        const int fidx = g * 256 + t;
        const int l = fidx >> 4;
        const int f = fidx & 15;
        seq_t[(4 * f + 0) * 129 + l] = sv[g].x;
        seq_t[(4 * f + 1) * 129 + l] = sv[g].y;
        seq_t[(4 * f + 2) * 129 + l] = sv[g].z;
        seq_t[(4 * f + 3) * 129 + l] = sv[g].w;
    }
    __syncthreads();

    // ---- scores: wave w = (head-pair hp, row-half); 2 heads per thread ----
    const int hp = w & 1;
    const int lhalf = w >> 1;
    const int l = lhalf * 64 + lane;

    float accA[8], accB[8];
    #pragma unroll
    for (int j = 0; j < 8; ++j) {
        accA[j] = cvl[hp * 8 + j];
        accB[j] = cvl[(hp + 2) * 8 + j];
    }

    const float4* wtA = reinterpret_cast<const float4*>(wt + hp * 512);
    const float4* wtB = reinterpret_cast<const float4*>(wt + (hp + 2) * 512);
    #pragma unroll 4
    for (int k = 0; k < 64; ++k) {
        const float svv = seq_t[k * 129 + l];
        const float4 a0 = wtA[k * 2], a1 = wtA[k * 2 + 1];   // uniform ds_read_b128
        const float4 b0 = wtB[k * 2], b1v = wtB[k * 2 + 1];
        accA[0]=fmaf(svv,a0.x,accA[0]); accA[1]=fmaf(svv,a0.y,accA[1]);
        accA[2]=fmaf(svv,a0.z,accA[2]); accA[3]=fmaf(svv,a0.w,accA[3]);
        accA[4]=fmaf(svv,a1.x,accA[4]); accA[5]=fmaf(svv,a1.y,accA[5]);
        accA[6]=fmaf(svv,a1.z,accA[6]); accA[7]=fmaf(svv,a1.w,accA[7]);
        accB[0]=fmaf(svv,b0.x,accB[0]); accB[1]=fmaf(svv,b0.y,accB[1]);
        accB[2]=fmaf(svv,b0.z,accB[2]); accB[3]=fmaf(svv,b0.w,accB[3]);
        accB[4]=fmaf(svv,b1v.x,accB[4]); accB[5]=fmaf(svv,b1v.y,accB[5]);
        accB[6]=fmaf(svv,b1v.z,accB[6]); accB[7]=fmaf(svv,b1v.w,accB[7]);
    }

    {
        const float4 w20 = *reinterpret_cast<const float4*>(W2);
        const float4 w21 = *reinterpret_cast<const float4*>(W2 + 4);
        const float bb = b2[0];
        float scA = bb, scB = bb;
        scA = fmaf(w20.x, sigm(accA[0]), scA); scA = fmaf(w20.y, sigm(accA[1]), scA);
        scA = fmaf(w20.z, sigm(accA[2]), scA); scA = fmaf(w20.w, sigm(accA[3]), scA);
        scA = fmaf(w21.x, sigm(accA[4]), scA); scA = fmaf(w21.y, sigm(accA[5]), scA);
        scA = fmaf(w21.z, sigm(accA[6]), scA); scA = fmaf(w21.w, sigm(accA[7]), scA);
        scB = fmaf(w20.x, sigm(accB[0]), scB); scB = fmaf(w20.y, sigm(accB[1]), scB);
        scB = fmaf(w20.z, sigm(accB[2]), scB); scB = fmaf(w20.w, sigm(accB[3]), scB);
        scB = fmaf(w21.x, sigm(accB[4]), scB); scB = fmaf(w21.y, sigm(accB[5]), scB);
        scB = fmaf(w21.z, sigm(accB[6]), scB); scB = fmaf(w21.w, sigm(accB[7]), scB);
        att_l[hp * 128 + l]       = sigm(scA);
        att_l[(hp + 2) * 128 + l] = sigm(scB);
    }
    __syncthreads();

    // ---- coalesced att store: 512 contiguous floats per block ----
    {
        float* dst = att_out + ((size_t)n * LL + l0) * 4;
        #pragma unroll
        for (int r = 0; r < 2; ++r) {
            const int idx = r * 256 + t;
            dst[idx] = att_l[(idx & 3) * 128 + (idx >> 2)];
        }
    }

    // ---- T[h][k] = sum_l att[h][l] * seq[l][k]; att via uniform float4 ----
    {
        const int h = w, k = lane;
        const float4* arow = reinterpret_cast<const float4*>(att_l + h * 128);
        float tacc = 0.f;
        #pragma unroll 4
        for (int li4 = 0; li4 < 32; ++li4) {
            const float4 a = arow[li4];                 // uniform b128
            tacc = fmaf(a.x, seq_t[k * 129 + li4 * 4 + 0], tacc);
            tacc = fmaf(a.y, seq_t[k * 129 + li4 * 4 + 1], tacc);
            tacc = fmaf(a.z, seq_t[k * 129 + li4 * 4 + 2], tacc);
            tacc = fmaf(a.w, seq_t[k * 129 + li4 * 4 + 3], tacc);
        }
        T_l[t] = tacc;
    }
    __syncthreads();

    // ---- out[q] += sum_p T[p] * Zt[p][q]; Zt lane-coalesced, T uniform ----
    {
        const int q = t & 63, wq = t >> 6;
        float s = 0.f;
        #pragma unroll 8
        for (int i = 0; i < 64; ++i) {
            const int p = wq * 64 + i;
            s = fmaf(T_l[p], Zt[p * 64 + q], s);
        }
        op[t] = s;
    }
    __syncthreads();
    if (t < 64) {
        const float s = op[t] + op[64 + t] + op[128 + t] + op[192 + t];
        atomicAdd(out + n * 64 + t, s);
    }
}

extern "C" void kernel_launch(void* const* d_in, const int* in_sizes, int n_in,
                              void* d_out, int out_size, void* d_ws, size_t ws_size,
                              hipStream_t stream) {
    const float* seq    = (const float*)d_in[0];
    const float* target = (const float*)d_in[1];
    const float* memv   = (const float*)d_in[2];
    const float* Wk     = (const float*)d_in[3];
    const float* Wq     = (const float*)d_in[4];
    const float* Wv     = (const float*)d_in[5];
    const float* Wu     = (const float*)d_in[6];
    const float* bu     = (const float*)d_in[7];
    const float* W1     = (const float*)d_in[8];
    const float* b1     = (const float*)d_in[9];
    const float* W2     = (const float*)d_in[10];
    const float* b2     = (const float*)d_in[11];

    float* out = (float*)d_out;             // [128*64]
    float* att = out + NN * DD;             // [128*1024*4]

    float* ws  = (float*)d_ws;
    float* Wtg = ws + WS_WT;
    float* cvg = ws + WS_C;
    float* Ztw = ws + WS_ZT;

    precompute_kernel<<<608, 256, 0, stream>>>(target, memv, Wk, Wq, Wv, Wu, W1, b1,
                                               bu, Wtg, cvg, Ztw, out);
    main_kernel<<<NN * NCHUNK, 256, 0, stream>>>(seq, Wtg, cvg, W2, b2, Ztw,
                                                 att, out);
}

// Round 5
// 26.673 us; speedup vs baseline: 2.2753x; 1.2288x over previous
//
#include <hip/hip_runtime.h>
#include <math.h>

// Problem constants
#define NN 128
#define LL 1024
#define HH 4
#define DD 64
#define NCHUNK 8          // chunks per n (128 rows each)
#define CROWS 128

// workspace layout (floats)
//   Zt  : [256(p=h*64+k)][64 q]   @ 0       (16384)
//   cv  : [N][32(hj)]             @ 16384   (4096)
//   Wtb : [N][32(hj)][64 k] bf16  @ 20480   (131072 floats worth)
#define WS_ZT  0
#define WS_C   16384
#define WS_WTB 20480

typedef __attribute__((ext_vector_type(8))) short short8;
typedef __attribute__((ext_vector_type(4))) float f32x4;

__device__ __forceinline__ float sigm(float x) {
    return __builtin_amdgcn_rcpf(1.f + __expf(-x));
}

__device__ __forceinline__ unsigned short f2bf(float x) {
    union { float f; unsigned u; } v; v.f = x;
    unsigned r = v.u + 0x7FFFu + ((v.u >> 16) & 1u);   // RNE
    return (unsigned short)(r >> 16);
}

__device__ __forceinline__ short8 pack_bf8(float4 a, float4 b) {
    short8 r;
    r[0] = (short)f2bf(a.x); r[1] = (short)f2bf(a.y);
    r[2] = (short)f2bf(a.z); r[3] = (short)f2bf(a.w);
    r[4] = (short)f2bf(b.x); r[5] = (short)f2bf(b.y);
    r[6] = (short)f2bf(b.z); r[7] = (short)f2bf(b.w);
    return r;
}

// ---------------------------------------------------------------------------
// K1: blocks 0..31   : out[n,q] = bu[q]          (init for K2's atomics)
//     blocks 32..95  : Zt[p,q]  = sum_d Wu[q,h*64+d]*Wv[h*64+d,k]  (p=h*64+k)
//     blocks 96..607 : per-(n,h) v, w, c, Wt(bf16, [hj][k] layout)
// ---------------------------------------------------------------------------
__global__ void __launch_bounds__(256) precompute_kernel(
    const float* __restrict__ target, const float* __restrict__ memv,
    const float* __restrict__ Wk, const float* __restrict__ Wq,
    const float* __restrict__ Wv, const float* __restrict__ Wu,
    const float* __restrict__ W1, const float* __restrict__ b1,
    const float* __restrict__ bu,
    unsigned short* __restrict__ Wtb, float* __restrict__ cvg,
    float* __restrict__ Zt, float* __restrict__ out)
{
    const int b = blockIdx.x;
    const int t = threadIdx.x;

    if (b < 32) {
        const int idx = b * 256 + t;          // 8192 = 128*64
        out[idx] = bu[idx & 63];
        return;
    }
    if (b < 96) {
        // Zt: q = b-32; t = p = h*64+k. Wv read coalesced (k on lanes).
        const int q = b - 32;
        const int h = t >> 6, k = t & 63;
        float s = 0.f;
        #pragma unroll 8
        for (int d = 0; d < 64; ++d)
            s = fmaf(Wu[q * 256 + h * 64 + d], Wv[(h * 64 + d) * 64 + k], s);
        Zt[t * 64 + q] = s;
        return;
    }

    const int nh = b - 96;
    const int n = nh >> 2, h = nh & 3;

    __shared__ __align__(16) float tl[64];
    __shared__ __align__(16) float ml[64];
    __shared__ float vh[64];
    __shared__ float wh[64 * 8];              // [d][j]
    __shared__ float cp[64];

    if (t < 64)       tl[t] = target[n * 64 + t];
    else if (t < 128) ml[t - 64] = memv[n * 64 + (t - 64)];
    __syncthreads();

    // ---- v[d] = sum_k Wq[h*64+d, k] * target[k]; (d, k-quarter) on threads ----
    {
        const int d = t >> 2, kq = t & 3;
        const float4* wq4 = reinterpret_cast<const float4*>(Wq + (h * 64 + d) * 64 + kq * 16);
        const float4* tl4 = reinterpret_cast<const float4*>(tl + kq * 16);
        float s = 0.f;
        #pragma unroll
        for (int c = 0; c < 4; ++c) {
            const float4 a = wq4[c], bb = tl4[c];
            s = fmaf(a.x, bb.x, s); s = fmaf(a.y, bb.y, s);
            s = fmaf(a.z, bb.z, s); s = fmaf(a.w, bb.w, s);
        }
        s += __shfl_xor(s, 1);
        s += __shfl_xor(s, 2);
        if (kq == 0) vh[d] = s;
    }
    __syncthreads();

    // ---- w[d][j] = -W1[j,d] - W1[j,128+d] + W1[j,64+d]*v[d] + W1[j,192+d]*m[d] ----
    {
        const int d = t & 63, jh = t >> 6;
        const float vv = vh[d], mm = ml[d];
        #pragma unroll
        for (int r = 0; r < 2; ++r) {
            const int j = jh + r * 4;
            float wv = -W1[j * 256 + d] - W1[j * 256 + 128 + d];
            wv = fmaf(W1[j * 256 + 64 + d], vv, wv);
            wv = fmaf(W1[j * 256 + 192 + d], mm, wv);
            wh[d * 8 + j] = wv;
        }
    }
    // ---- c[j] partials ----
    if (t < 64) {
        const int j = t >> 3, sl = t & 7;
        float s = 0.f;
        #pragma unroll
        for (int d8 = 0; d8 < 8; ++d8) {
            const int d = sl * 8 + d8;
            s = fmaf(W1[j * 256 + d], vh[d], s);
            s = fmaf(W1[j * 256 + 128 + d], ml[d], s);
        }
        cp[t] = s;
    }
    __syncthreads();
    if (t < 8) {
        float s = b1[t];
        #pragma unroll
        for (int sl = 0; sl < 8; ++sl) s += cp[t * 8 + sl];
        cvg[n * 32 + h * 8 + t] = s;
    }

    // ---- Wt[hj][k] = sum_d Wk[h*64+d, k] * w[d][j]; k on lanes (coalesced) ----
    {
        const int k = t & 63, jp = t >> 6;
        float s0 = 0.f, s1 = 0.f;
        #pragma unroll 8
        for (int d = 0; d < 64; ++d) {
            const float wk = Wk[(h * 64 + d) * 64 + k];
            s0 = fmaf(wk, wh[d * 8 + jp], s0);       // uniform LDS reads
            s1 = fmaf(wk, wh[d * 8 + jp + 4], s1);
        }
        unsigned short* dst = Wtb + ((size_t)n * 32 + h * 8) * 64;
        dst[jp * 64 + k]       = f2bf(s0);
        dst[(jp + 4) * 64 + k] = f2bf(s1);
    }
}

// ---------------------------------------------------------------------------
// K2: per (n, 128-row chunk):
//   score GEMM via MFMA: S^T[hj, l] = Wt[hj,:k] . seq[l,:k]^T  (bf16 in, f32 out)
//     A-frag = Wt bf16 from LDS (padded rows), B-frag = seq from GLOBAL (cvt)
//   -> sigmoid MLP (j-reduce via shfl_xor 16) -> att_l[l][h] (LDS)
//   -> T[h][k] = sum_l att*seq (seq re-read from global, L1-hot)
//   -> out[q] += sum_p T[p]*Zt[p][q]  (atomic)
// ---------------------------------------------------------------------------
__global__ void __launch_bounds__(256, 4) main_kernel(
    const float* __restrict__ seq, const unsigned short* __restrict__ Wtb,
    const float* __restrict__ cvg, const float* __restrict__ W2,
    const float* __restrict__ b2, const float* __restrict__ Zt,
    float* __restrict__ att_out, float* __restrict__ out)
{
    const int n = blockIdx.x >> 3;
    const int chunk = blockIdx.x & 7;
    const int l0 = chunk * CROWS;
    const int t = threadIdx.x;
    const int lane = t & 63;
    const int w = t >> 6;

    __shared__ __align__(16) short wt_lds[32 * 72];   // [hj][72]: pad rows 16B
    __shared__ float cvl[32];
    __shared__ __align__(16) float att_l[512];        // [l][h]
    __shared__ __align__(16) float Tp_l[4][256];      // per-wave partial T
    __shared__ float T_l[256];                        // [p = h*64+k]
    __shared__ float op[256];

    // ---- stage Wt (bf16, 4KB) + cv into LDS ----
    {
        const int row = t >> 3, seg = t & 7;
        const int4 wv = *reinterpret_cast<const int4*>(
            Wtb + ((size_t)n * 32 + row) * 64 + seg * 8);
        *reinterpret_cast<int4*>(wt_lds + row * 72 + seg * 8) = wv;
    }
    if (t < 32) cvl[t] = cvg[n * 32 + t];
    __syncthreads();

    const float* sbase = seq + ((size_t)n * LL + l0) * 64;

    // ---- score MFMAs: wave w -> rowtile rt (hj 16-block), coltiles ctbase..+3 ----
    const int rt = w & 1;
    const int ctbase = (w >> 1) * 4;
    const int g = lane >> 4;          // k-group / C-row group
    const int cidx = lane & 15;       // col within tile

    short8 afrag[2];
    #pragma unroll
    for (int ks = 0; ks < 2; ++ks)
        afrag[ks] = *reinterpret_cast<const short8*>(
            wt_lds + (rt * 16 + cidx) * 72 + ks * 32 + g * 8);

    f32x4 acc[4];
    #pragma unroll
    for (int ct = 0; ct < 4; ++ct)
        #pragma unroll
        for (int r = 0; r < 4; ++r)
            acc[ct][r] = cvl[rt * 16 + g * 4 + r];

    #pragma unroll
    for (int ct = 0; ct < 4; ++ct) {
        const int l = (ctbase + ct) * 16 + cidx;
        const float* rowp = sbase + l * 64 + g * 8;
        const float4 b00 = *reinterpret_cast<const float4*>(rowp);
        const float4 b01 = *reinterpret_cast<const float4*>(rowp + 4);
        const float4 b10 = *reinterpret_cast<const float4*>(rowp + 32);
        const float4 b11 = *reinterpret_cast<const float4*>(rowp + 36);
        const short8 bf0 = pack_bf8(b00, b01);
        const short8 bf1 = pack_bf8(b10, b11);
        acc[ct] = __builtin_amdgcn_mfma_f32_16x16x32_bf16(afrag[0], bf0, acc[ct], 0, 0, 0);
        acc[ct] = __builtin_amdgcn_mfma_f32_16x16x32_bf16(afrag[1], bf1, acc[ct], 0, 0, 0);
    }

    // ---- MLP: hmid = sigm(score); partial j-sum; partner group via shfl_xor 16 ----
    {
        const float4 w2v = *reinterpret_cast<const float4*>(W2 + 4 * (g & 1));
        const float b2v = b2[0];
        #pragma unroll
        for (int ct = 0; ct < 4; ++ct) {
            float local = w2v.x * sigm(acc[ct][0]);
            local = fmaf(w2v.y, sigm(acc[ct][1]), local);
            local = fmaf(w2v.z, sigm(acc[ct][2]), local);
            local = fmaf(w2v.w, sigm(acc[ct][3]), local);
            local += __shfl_xor(local, 16);
            const float attv = sigm(b2v + local);
            if ((lane & 16) == 0) {
                const int l = (ctbase + ct) * 16 + cidx;
                const int h = 2 * rt + (g >> 1);
                att_l[l * 4 + h] = attv;
            }
        }
    }
    __syncthreads();

    // ---- att store: 512 contiguous floats ([l][h] == reference [l,h] layout) ----
    {
        float* dst = att_out + ((size_t)n * LL + l0) * 4;
        dst[t] = att_l[t];
        dst[256 + t] = att_l[256 + t];
    }

    // ---- T partials: wave w covers l in [32w, 32w+32); lane = k ----
    {
        float th0 = 0.f, th1 = 0.f, th2 = 0.f, th3 = 0.f;
        const float* sq = sbase + (w * 32) * 64 + lane;
        #pragma unroll 4
        for (int li = 0; li < 32; ++li) {
            const float s = sq[li * 64];                      // coalesced, L1-hot
            const float4 a = *reinterpret_cast<const float4*>(att_l + (w * 32 + li) * 4);
            th0 = fmaf(a.x, s, th0); th1 = fmaf(a.y, s, th1);
            th2 = fmaf(a.z, s, th2); th3 = fmaf(a.w, s, th3);
        }
        Tp_l[w][0 * 64 + lane] = th0;
        Tp_l[w][1 * 64 + lane] = th1;
        Tp_l[w][2 * 64 + lane] = th2;
        Tp_l[w][3 * 64 + lane] = th3;
    }
    __syncthreads();

    T_l[t] = Tp_l[0][t] + Tp_l[1][t] + Tp_l[2][t] + Tp_l[3][t];
    __syncthreads();

    // ---- out[q] += sum_p T[p] * Zt[p][q]; Zt lane-coalesced, T uniform ----
    {
        const int q = t & 63, wq = t >> 6;
        float s = 0.f;
        #pragma unroll 8
        for (int i = 0; i < 64; ++i) {
            const int p = wq * 64 + i;
            s = fmaf(T_l[p], Zt[p * 64 + q], s);
        }
        op[t] = s;
    }
    __syncthreads();
    if (t < 64) {
        const float s = op[t] + op[64 + t] + op[128 + t] + op[192 + t];
        atomicAdd(out + n * 64 + t, s);
    }
}

extern "C" void kernel_launch(void* const* d_in, const int* in_sizes, int n_in,
                              void* d_out, int out_size, void* d_ws, size_t ws_size,
                              hipStream_t stream) {
    const float* seq    = (const float*)d_in[0];
    const float* target = (const float*)d_in[1];
    const float* memv   = (const float*)d_in[2];
    const float* Wk     = (const float*)d_in[3];
    const float* Wq     = (const float*)d_in[4];
    const float* Wv     = (const float*)d_in[5];
    const float* Wu     = (const float*)d_in[6];
    const float* bu     = (const float*)d_in[7];
    const float* W1     = (const float*)d_in[8];
    const float* b1     = (const float*)d_in[9];
    const float* W2     = (const float*)d_in[10];
    const float* b2     = (const float*)d_in[11];

    float* out = (float*)d_out;             // [128*64]
    float* att = out + NN * DD;             // [128*1024*4]

    float* ws  = (float*)d_ws;
    float* Ztw = ws + WS_ZT;
    float* cvg = ws + WS_C;
    unsigned short* Wtb = (unsigned short*)(ws + WS_WTB);

    precompute_kernel<<<608, 256, 0, stream>>>(target, memv, Wk, Wq, Wv, Wu, W1, b1,
                                               bu, Wtb, cvg, Ztw, out);
    main_kernel<<<NN * NCHUNK, 256, 0, stream>>>(seq, Wtb, cvg, W2, b2, Ztw,
                                                 att, out);
}

// Round 6
// 21.656 us; speedup vs baseline: 2.8024x; 1.2317x over previous
//
#include <hip/hip_runtime.h>
#include <math.h>

// Problem constants
#define NN 128
#define LL 1024
#define HH 4
#define DD 64
#define NCHUNK 8          // chunks per n (128 rows each)
#define CROWS 128

// workspace layout (floats)
//   Zt  : [256(p=h*64+k)][64 q]   @ 0       (16384)
//   cv  : [N][32(hj)]             @ 16384   (4096)
//   Wtb : [N][32(hj)][64 k] bf16  @ 20480
#define WS_ZT  0
#define WS_C   16384
#define WS_WTB 20480

typedef __attribute__((ext_vector_type(8))) short short8;
typedef __attribute__((ext_vector_type(4))) float f32x4;

__device__ __forceinline__ float sigm(float x) {
    return __builtin_amdgcn_rcpf(1.f + __expf(-x));
}

__device__ __forceinline__ unsigned short f2bf(float x) {
    union { float f; unsigned u; } v; v.f = x;
    unsigned r = v.u + 0x7FFFu + ((v.u >> 16) & 1u);   // RNE
    return (unsigned short)(r >> 16);
}

__device__ __forceinline__ short8 pack_bf8(float4 a, float4 b) {
    short8 r;
    r[0] = (short)f2bf(a.x); r[1] = (short)f2bf(a.y);
    r[2] = (short)f2bf(a.z); r[3] = (short)f2bf(a.w);
    r[4] = (short)f2bf(b.x); r[5] = (short)f2bf(b.y);
    r[6] = (short)f2bf(b.z); r[7] = (short)f2bf(b.w);
    return r;
}

// ---------------------------------------------------------------------------
// K1: blocks 0..31   : out[n,q] = bu[q]          (init for K2's atomics)
//     blocks 32..95  : Zt[p,q]  = sum_d Wu[q,h*64+d]*Wv[h*64+d,k]  (p=h*64+k)
//     blocks 96..607 : per-(n,h) v, w, c, Wt(bf16, [hj][k] layout)
// ---------------------------------------------------------------------------
__global__ void __launch_bounds__(256) precompute_kernel(
    const float* __restrict__ target, const float* __restrict__ memv,
    const float* __restrict__ Wk, const float* __restrict__ Wq,
    const float* __restrict__ Wv, const float* __restrict__ Wu,
    const float* __restrict__ W1, const float* __restrict__ b1,
    const float* __restrict__ bu,
    unsigned short* __restrict__ Wtb, float* __restrict__ cvg,
    float* __restrict__ Zt, float* __restrict__ out)
{
    const int b = blockIdx.x;
    const int t = threadIdx.x;

    if (b < 32) {
        const int idx = b * 256 + t;          // 8192 = 128*64
        out[idx] = bu[idx & 63];
        return;
    }
    if (b < 96) {
        // Zt: q = b-32; t = p = h*64+k. Wv read coalesced (k on lanes).
        const int q = b - 32;
        const int h = t >> 6, k = t & 63;
        float s = 0.f;
        #pragma unroll 8
        for (int d = 0; d < 64; ++d)
            s = fmaf(Wu[q * 256 + h * 64 + d], Wv[(h * 64 + d) * 64 + k], s);
        Zt[t * 64 + q] = s;
        return;
    }

    const int nh = b - 96;
    const int n = nh >> 2, h = nh & 3;

    __shared__ __align__(16) float tl[64];
    __shared__ __align__(16) float ml[64];
    __shared__ float vh[64];
    __shared__ float wh[64 * 8];              // [d][j]
    __shared__ float cp[64];

    if (t < 64)       tl[t] = target[n * 64 + t];
    else if (t < 128) ml[t - 64] = memv[n * 64 + (t - 64)];
    __syncthreads();

    // ---- v[d] = sum_k Wq[h*64+d, k] * target[k]; (d, k-quarter) on threads ----
    {
        const int d = t >> 2, kq = t & 3;
        const float4* wq4 = reinterpret_cast<const float4*>(Wq + (h * 64 + d) * 64 + kq * 16);
        const float4* tl4 = reinterpret_cast<const float4*>(tl + kq * 16);
        float s = 0.f;
        #pragma unroll
        for (int c = 0; c < 4; ++c) {
            const float4 a = wq4[c], bb = tl4[c];
            s = fmaf(a.x, bb.x, s); s = fmaf(a.y, bb.y, s);
            s = fmaf(a.z, bb.z, s); s = fmaf(a.w, bb.w, s);
        }
        s += __shfl_xor(s, 1);
        s += __shfl_xor(s, 2);
        if (kq == 0) vh[d] = s;
    }
    __syncthreads();

    // ---- w[d][j] = -W1[j,d] - W1[j,128+d] + W1[j,64+d]*v[d] + W1[j,192+d]*m[d] ----
    {
        const int d = t & 63, jh = t >> 6;
        const float vv = vh[d], mm = ml[d];
        #pragma unroll
        for (int r = 0; r < 2; ++r) {
            const int j = jh + r * 4;
            float wv = -W1[j * 256 + d] - W1[j * 256 + 128 + d];
            wv = fmaf(W1[j * 256 + 64 + d], vv, wv);
            wv = fmaf(W1[j * 256 + 192 + d], mm, wv);
            wh[d * 8 + j] = wv;
        }
    }
    // ---- c[j] partials ----
    if (t < 64) {
        const int j = t >> 3, sl = t & 7;
        float s = 0.f;
        #pragma unroll
        for (int d8 = 0; d8 < 8; ++d8) {
            const int d = sl * 8 + d8;
            s = fmaf(W1[j * 256 + d], vh[d], s);
            s = fmaf(W1[j * 256 + 128 + d], ml[d], s);
        }
        cp[t] = s;
    }
    __syncthreads();
    if (t < 8) {
        float s = b1[t];
        #pragma unroll
        for (int sl = 0; sl < 8; ++sl) s += cp[t * 8 + sl];
        cvg[n * 32 + h * 8 + t] = s;
    }

    // ---- Wt[hj][k] = sum_d Wk[h*64+d, k] * w[d][j]; k on lanes (coalesced) ----
    {
        const int k = t & 63, jp = t >> 6;
        float s0 = 0.f, s1 = 0.f;
        #pragma unroll 8
        for (int d = 0; d < 64; ++d) {
            const float wk = Wk[(h * 64 + d) * 64 + k];
            s0 = fmaf(wk, wh[d * 8 + jp], s0);       // uniform LDS reads
            s1 = fmaf(wk, wh[d * 8 + jp + 4], s1);
        }
        unsigned short* dst = Wtb + ((size_t)n * 32 + h * 8) * 64;
        dst[jp * 64 + k]       = f2bf(s0);
        dst[(jp + 4) * 64 + k] = f2bf(s1);
    }
}

// ---------------------------------------------------------------------------
// K2: per (n, 128-row chunk):
//   stage seq chunk as bf16 in LDS (coalesced global float4 -> pack -> b128)
//   score GEMM via MFMA: S^T[hj, l] = Wt[hj,:k] . seq[l,:k]^T
//     A-frag = Wt bf16 (LDS), B-frag = seq bf16 (LDS, row stride 72)
//   -> sigmoid MLP (j-reduce via shfl_xor 16) -> att_l[l][h]
//   -> T[h][k] = sum_l att*seq (fp32 seq re-read from global, coalesced/L2)
//   -> out[q] += sum_p T[p]*Zt[p][q]  (atomic)
// ---------------------------------------------------------------------------
__global__ void __launch_bounds__(256, 4) main_kernel(
    const float* __restrict__ seq, const unsigned short* __restrict__ Wtb,
    const float* __restrict__ cvg, const float* __restrict__ W2,
    const float* __restrict__ b2, const float* __restrict__ Zt,
    float* __restrict__ att_out, float* __restrict__ out)
{
    const int n = blockIdx.x >> 3;
    const int chunk = blockIdx.x & 7;
    const int l0 = chunk * CROWS;
    const int t = threadIdx.x;
    const int lane = t & 63;
    const int w = t >> 6;

    __shared__ __align__(16) short seq_bf[128 * 72];  // [l][k] bf16, 144B rows
    __shared__ __align__(16) short wt_lds[32 * 72];   // [hj][k] bf16
    __shared__ float cvl[32];
    __shared__ __align__(16) float att_l[512];        // [l][h]
    __shared__ __align__(16) float Tp_l[4][256];      // per-wave partial T
    __shared__ float T_l[256];                        // [p = h*64+k]
    __shared__ float op[256];
    // total ~31.4 KB

    const float* sbase = seq + ((size_t)n * LL + l0) * 64;

    // ---- stage seq chunk as bf16: 4 x (two float4 = 32B contig per thread) ----
    #pragma unroll
    for (int g = 0; g < 4; ++g) {
        const int p4 = g * 256 + t;           // 8-float group id (1024 total)
        const int l = p4 >> 3, seg = p4 & 7;
        const float* rp = sbase + l * 64 + seg * 8;
        const float4 a = *reinterpret_cast<const float4*>(rp);
        const float4 bb = *reinterpret_cast<const float4*>(rp + 4);
        *reinterpret_cast<short8*>(seq_bf + l * 72 + seg * 8) = pack_bf8(a, bb);
    }
    // ---- stage Wt (bf16, 4KB) + cv ----
    {
        const int row = t >> 3, seg = t & 7;
        const int4 wv = *reinterpret_cast<const int4*>(
            Wtb + ((size_t)n * 32 + row) * 64 + seg * 8);
        *reinterpret_cast<int4*>(wt_lds + row * 72 + seg * 8) = wv;
    }
    if (t < 32) cvl[t] = cvg[n * 32 + t];
    __syncthreads();

    // ---- score MFMAs: wave w -> rowtile rt (hj 16-block), coltiles ctbase..+3 ----
    const int rt = w & 1;
    const int ctbase = (w >> 1) * 4;
    const int g = lane >> 4;          // k-group / C-row group
    const int cidx = lane & 15;       // col within tile

    short8 afrag[2];
    #pragma unroll
    for (int ks = 0; ks < 2; ++ks)
        afrag[ks] = *reinterpret_cast<const short8*>(
            wt_lds + (rt * 16 + cidx) * 72 + ks * 32 + g * 8);

    f32x4 acc[4];
    #pragma unroll
    for (int ct = 0; ct < 4; ++ct)
        #pragma unroll
        for (int r = 0; r < 4; ++r)
            acc[ct][r] = cvl[rt * 16 + g * 4 + r];

    #pragma unroll
    for (int ct = 0; ct < 4; ++ct) {
        const int l = (ctbase + ct) * 16 + cidx;
        const short8 bf0 = *reinterpret_cast<const short8*>(seq_bf + l * 72 + g * 8);
        const short8 bf1 = *reinterpret_cast<const short8*>(seq_bf + l * 72 + 32 + g * 8);
        acc[ct] = __builtin_amdgcn_mfma_f32_16x16x32_bf16(afrag[0], bf0, acc[ct], 0, 0, 0);
        acc[ct] = __builtin_amdgcn_mfma_f32_16x16x32_bf16(afrag[1], bf1, acc[ct], 0, 0, 0);
    }

    // ---- MLP: hmid = sigm(score); partial j-sum; partner group via shfl_xor 16 ----
    {
        const float4 w2v = *reinterpret_cast<const float4*>(W2 + 4 * (g & 1));
        const float b2v = b2[0];
        #pragma unroll
        for (int ct = 0; ct < 4; ++ct) {
            float local = w2v.x * sigm(acc[ct][0]);
            local = fmaf(w2v.y, sigm(acc[ct][1]), local);
            local = fmaf(w2v.z, sigm(acc[ct][2]), local);
            local = fmaf(w2v.w, sigm(acc[ct][3]), local);
            local += __shfl_xor(local, 16);
            const float attv = sigm(b2v + local);
            if ((lane & 16) == 0) {
                const int l = (ctbase + ct) * 16 + cidx;
                const int h = 2 * rt + (g >> 1);
                att_l[l * 4 + h] = attv;
            }
        }
    }
    __syncthreads();

    // ---- att store: 512 contiguous floats ([l][h] == reference layout) ----
    {
        float* dst = att_out + ((size_t)n * LL + l0) * 4;
        dst[t] = att_l[t];
        dst[256 + t] = att_l[256 + t];
    }

    // ---- T partials: wave w covers l in [32w, 32w+32); lane = k (fp32 seq) ----
    {
        float th0 = 0.f, th1 = 0.f, th2 = 0.f, th3 = 0.f;
        const float* sq = sbase + (w * 32) * 64 + lane;
        #pragma unroll 4
        for (int li = 0; li < 32; ++li) {
            const float s = sq[li * 64];                      // coalesced, L2-hot
            const float4 a = *reinterpret_cast<const float4*>(att_l + (w * 32 + li) * 4);
            th0 = fmaf(a.x, s, th0); th1 = fmaf(a.y, s, th1);
            th2 = fmaf(a.z, s, th2); th3 = fmaf(a.w, s, th3);
        }
        Tp_l[w][0 * 64 + lane] = th0;
        Tp_l[w][1 * 64 + lane] = th1;
        Tp_l[w][2 * 64 + lane] = th2;
        Tp_l[w][3 * 64 + lane] = th3;
    }
    __syncthreads();

    T_l[t] = Tp_l[0][t] + Tp_l[1][t] + Tp_l[2][t] + Tp_l[3][t];
    __syncthreads();

    // ---- out[q] += sum_p T[p] * Zt[p][q]; Zt lane-coalesced, T uniform ----
    {
        const int q = t & 63, wq = t >> 6;
        float s = 0.f;
        #pragma unroll 8
        for (int i = 0; i < 64; ++i) {
            const int p = wq * 64 + i;
            s = fmaf(T_l[p], Zt[p * 64 + q], s);
        }
        op[t] = s;
    }
    __syncthreads();
    if (t < 64) {
        const float s = op[t] + op[64 + t] + op[128 + t] + op[192 + t];
        atomicAdd(out + n * 64 + t, s);
    }
}

extern "C" void kernel_launch(void* const* d_in, const int* in_sizes, int n_in,
                              void* d_out, int out_size, void* d_ws, size_t ws_size,
                              hipStream_t stream) {
    const float* seq    = (const float*)d_in[0];
    const float* target = (const float*)d_in[1];
    const float* memv   = (const float*)d_in[2];
    const float* Wk     = (const float*)d_in[3];
    const float* Wq     = (const float*)d_in[4];
    const float* Wv     = (const float*)d_in[5];
    const float* Wu     = (const float*)d_in[6];
    const float* bu     = (const float*)d_in[7];
    const float* W1     = (const float*)d_in[8];
    const float* b1     = (const float*)d_in[9];
    const float* W2     = (const float*)d_in[10];
    const float* b2     = (const float*)d_in[11];

    float* out = (float*)d_out;             // [128*64]
    float* att = out + NN * DD;             // [128*1024*4]

    float* ws  = (float*)d_ws;
    float* Ztw = ws + WS_ZT;
    float* cvg = ws + WS_C;
    unsigned short* Wtb = (unsigned short*)(ws + WS_WTB);

    precompute_kernel<<<608, 256, 0, stream>>>(target, memv, Wk, Wq, Wv, Wu, W1, b1,
                                               bu, Wtb, cvg, Ztw, out);
    main_kernel<<<NN * NCHUNK, 256, 0, stream>>>(seq, Wtb, cvg, W2, b2, Ztw,
                                                 att, out);
}